// Round 1
// baseline (1906.896 us; speedup 1.0000x reference)
//
#include <hip/hip_runtime.h>
#include <math.h>

#define DMODEL 1024
#define NHEADS 16
#define DKDIM  64
#define SEQLEN 2048
#define NBATCH 4

// ================= fp32 tiled GEMM =================
// C = A[M,1024] @ W[1024,1024] + bias[1024]
// BM=BN=128, BK=16, 256 threads, 8x8 micro-tile per thread.
// PERMUTE=true writes C in [B, H, S, Dk] layout (for Q/K/V), else [M, N] flat.
template<bool PERMUTE>
__device__ __forceinline__
void gemm_body(const float* __restrict__ A, const float* __restrict__ W,
               const float* __restrict__ bias, float* __restrict__ C)
{
    __shared__ float As[16][132];   // stored transposed: As[k][m], pad->2-way max
    __shared__ float Bs[16][132];   // Bs[k][n]

    const int tid = threadIdx.x;
    const int tx = tid & 15, ty = tid >> 4;
    const int m0 = blockIdx.y << 7;
    const int n0 = blockIdx.x << 7;

    float acc[8][8];
#pragma unroll
    for (int i = 0; i < 8; ++i)
#pragma unroll
        for (int j = 0; j < 8; ++j) acc[i][j] = 0.f;

    const int ar = tid >> 2;          // 0..63
    const int ac = (tid & 3) << 2;    // 0,4,8,12
    const int br = tid >> 5;          // 0..7
    const int bc = (tid & 31) << 2;   // 0..124

    for (int k0 = 0; k0 < DMODEL; k0 += 16) {
        const float4 a0 = *(const float4*)&A[(size_t)(m0 + ar)      * DMODEL + k0 + ac];
        const float4 a1 = *(const float4*)&A[(size_t)(m0 + ar + 64) * DMODEL + k0 + ac];
        const float4 w0 = *(const float4*)&W[(size_t)(k0 + br)     * DMODEL + n0 + bc];
        const float4 w1 = *(const float4*)&W[(size_t)(k0 + br + 8) * DMODEL + n0 + bc];
        __syncthreads();   // previous iter's compute done before LDS overwrite
        As[ac+0][ar]    = a0.x; As[ac+1][ar]    = a0.y; As[ac+2][ar]    = a0.z; As[ac+3][ar]    = a0.w;
        As[ac+0][ar+64] = a1.x; As[ac+1][ar+64] = a1.y; As[ac+2][ar+64] = a1.z; As[ac+3][ar+64] = a1.w;
        *(float4*)&Bs[br][bc]   = w0;
        *(float4*)&Bs[br+8][bc] = w1;
        __syncthreads();
#pragma unroll
        for (int kk = 0; kk < 16; ++kk) {
            const float4 av0 = *(const float4*)&As[kk][(ty<<2)];
            const float4 av1 = *(const float4*)&As[kk][(ty<<2) + 64];
            const float4 bv0 = *(const float4*)&Bs[kk][(tx<<2)];
            const float4 bv1 = *(const float4*)&Bs[kk][(tx<<2) + 64];
            const float a[8] = {av0.x,av0.y,av0.z,av0.w, av1.x,av1.y,av1.z,av1.w};
            const float b[8] = {bv0.x,bv0.y,bv0.z,bv0.w, bv1.x,bv1.y,bv1.z,bv1.w};
#pragma unroll
            for (int i = 0; i < 8; ++i)
#pragma unroll
                for (int j = 0; j < 8; ++j)
                    acc[i][j] = fmaf(a[i], b[j], acc[i][j]);
        }
    }

    const float4 bias0 = *(const float4*)&bias[n0 + (tx<<2)];
    const float4 bias1 = *(const float4*)&bias[n0 + (tx<<2) + 64];
    const float bj[8] = {bias0.x,bias0.y,bias0.z,bias0.w, bias1.x,bias1.y,bias1.z,bias1.w};

#pragma unroll
    for (int i = 0; i < 8; ++i) {
        const int m = m0 + (ty<<2) + (i & 3) + ((i >> 2) << 6);
        float4 c0, c1;
        c0.x = acc[i][0]+bj[0]; c0.y = acc[i][1]+bj[1]; c0.z = acc[i][2]+bj[2]; c0.w = acc[i][3]+bj[3];
        c1.x = acc[i][4]+bj[4]; c1.y = acc[i][5]+bj[5]; c1.z = acc[i][6]+bj[6]; c1.w = acc[i][7]+bj[7];
        if (PERMUTE) {
            const int bb = m >> 11;                 // SEQLEN = 2048
            const int s  = m & (SEQLEN - 1);
            const int n_a = n0 + (tx<<2);
            const int n_b = n_a + 64;
            *(float4*)&C[(((size_t)(bb*NHEADS + (n_a>>6)) * SEQLEN + s) * DKDIM) + (n_a & 63)] = c0;
            *(float4*)&C[(((size_t)(bb*NHEADS + (n_b>>6)) * SEQLEN + s) * DKDIM) + (n_b & 63)] = c1;
        } else {
            float* p = &C[(size_t)m * DMODEL + n0 + (tx<<2)];
            *(float4*)p        = c0;
            *(float4*)(p + 64) = c1;
        }
    }
}

__global__ __launch_bounds__(256)
void qkv_gemm_kernel(const float* __restrict__ x,
                     const float* __restrict__ Wq, const float* __restrict__ bq,
                     const float* __restrict__ Wk, const float* __restrict__ bk,
                     const float* __restrict__ Wv, const float* __restrict__ bv,
                     float* __restrict__ q, float* __restrict__ k, float* __restrict__ v)
{
    const float* W; const float* bias; float* out;
    if (blockIdx.z == 0)      { W = Wq; bias = bq; out = q; }
    else if (blockIdx.z == 1) { W = Wk; bias = bk; out = k; }
    else                      { W = Wv; bias = bv; out = v; }
    gemm_body<true>(x, W, bias, out);
}

__global__ __launch_bounds__(256)
void out_gemm_kernel(const float* __restrict__ ctx, const float* __restrict__ Wo,
                     const float* __restrict__ bo, float* __restrict__ out)
{
    gemm_body<false>(ctx, Wo, bo, out);
}

// ================= fp32 flash attention =================
// One block = 64 q-rows of one (b,h). Online softmax over 32 K/V tiles of 64.
// 256 threads: tx=tid&15, ty=tid>>4. Scores: 4x4/thread, cols tx+16j (2-way LDS max).
__global__ __launch_bounds__(256)
void attn_kernel(const float* __restrict__ q, const float* __restrict__ k,
                 const float* __restrict__ v, float* __restrict__ ctx)
{
    __shared__ float Qs[64][68];
    __shared__ float Ks[64][68];
    __shared__ float Vs[64][68];
    __shared__ float Ps[64][68];
    __shared__ float m_s[64];
    __shared__ float l_s[64];

    const int tid = threadIdx.x;
    const int tx = tid & 15, ty = tid >> 4;
    const int qt = blockIdx.x;    // 0..31
    const int bh = blockIdx.y;    // 0..63

    const size_t base = (size_t)bh * SEQLEN * DKDIM;
    const float4* qsrc = (const float4*)(q + base + (size_t)qt * 64 * DKDIM);

    // Q tile, scaled by 1/sqrt(Dk) = 0.125
#pragma unroll
    for (int u = 0; u < 4; ++u) {
        const int f = tid + (u << 8);
        const float4 t = qsrc[f];
        const int r = f >> 4, c = (f & 15) << 2;
        Qs[r][c  ] = t.x * 0.125f;
        Qs[r][c+1] = t.y * 0.125f;
        Qs[r][c+2] = t.z * 0.125f;
        Qs[r][c+3] = t.w * 0.125f;
    }
    if (tid < 64) { m_s[tid] = -INFINITY; l_s[tid] = 0.f; }

    float o[4][4];
#pragma unroll
    for (int i = 0; i < 4; ++i)
#pragma unroll
        for (int j = 0; j < 4; ++j) o[i][j] = 0.f;

    for (int kt = 0; kt < SEQLEN/64; ++kt) {
        __syncthreads();   // prev PV done; Qs/m_s init visible on first iter
        const float4* ksrc = (const float4*)(k + base + (size_t)kt * 64 * DKDIM);
        const float4* vsrc = (const float4*)(v + base + (size_t)kt * 64 * DKDIM);
#pragma unroll
        for (int u = 0; u < 4; ++u) {
            const int f = tid + (u << 8);
            const int r = f >> 4, c = (f & 15) << 2;
            const float4 tk = ksrc[f];
            Ks[r][c] = tk.x; Ks[r][c+1] = tk.y; Ks[r][c+2] = tk.z; Ks[r][c+3] = tk.w;
            const float4 tv = vsrc[f];
            Vs[r][c] = tv.x; Vs[r][c+1] = tv.y; Vs[r][c+2] = tv.z; Vs[r][c+3] = tv.w;
        }
        __syncthreads();

        // ---- scores: s[i][j] = Qs[ty*4+i][:] . Ks[tx+16j][:] ----
        float s[4][4];
#pragma unroll
        for (int i = 0; i < 4; ++i)
#pragma unroll
            for (int j = 0; j < 4; ++j) s[i][j] = 0.f;

#pragma unroll 4
        for (int d4 = 0; d4 < DKDIM; d4 += 4) {
            float4 qv[4], kv[4];
#pragma unroll
            for (int i = 0; i < 4; ++i) qv[i] = *(const float4*)&Qs[(ty<<2)+i][d4];
#pragma unroll
            for (int j = 0; j < 4; ++j) kv[j] = *(const float4*)&Ks[tx + (j<<4)][d4];
#pragma unroll
            for (int i = 0; i < 4; ++i)
#pragma unroll
                for (int j = 0; j < 4; ++j) {
                    s[i][j] = fmaf(qv[i].x, kv[j].x, s[i][j]);
                    s[i][j] = fmaf(qv[i].y, kv[j].y, s[i][j]);
                    s[i][j] = fmaf(qv[i].z, kv[j].z, s[i][j]);
                    s[i][j] = fmaf(qv[i].w, kv[j].w, s[i][j]);
                }
        }

        // ---- online softmax (rows wave-private: reduce over 16 tx lanes) ----
        float al[4];
#pragma unroll
        for (int i = 0; i < 4; ++i) {
            const int row = (ty<<2) + i;
            float mx = fmaxf(fmaxf(s[i][0], s[i][1]), fmaxf(s[i][2], s[i][3]));
#pragma unroll
            for (int msk = 1; msk < 16; msk <<= 1) mx = fmaxf(mx, __shfl_xor(mx, msk));
            const float mprev = m_s[row];
            const float mnew  = fmaxf(mprev, mx);
            float psum = 0.f;
#pragma unroll
            for (int j = 0; j < 4; ++j) {
                const float p = __expf(s[i][j] - mnew);
                Ps[row][tx + (j<<4)] = p;
                psum += p;
            }
#pragma unroll
            for (int msk = 1; msk < 16; msk <<= 1) psum += __shfl_xor(psum, msk);
            al[i] = __expf(mprev - mnew);
            if (tx == 0) { m_s[row] = mnew; l_s[row] = l_s[row]*al[i] + psum; }
        }
        __syncthreads();   // Ps visible

        // ---- rescale + PV: o[i][:] += P[row][:] @ V ----
#pragma unroll
        for (int i = 0; i < 4; ++i)
#pragma unroll
            for (int j = 0; j < 4; ++j) o[i][j] *= al[i];

#pragma unroll 8
        for (int kk = 0; kk < 64; ++kk) {
            const float4 vv = *(const float4*)&Vs[kk][(tx<<2)];
#pragma unroll
            for (int i = 0; i < 4; ++i) {
                const float p = Ps[(ty<<2)+i][kk];
                o[i][0] = fmaf(p, vv.x, o[i][0]);
                o[i][1] = fmaf(p, vv.y, o[i][1]);
                o[i][2] = fmaf(p, vv.z, o[i][2]);
                o[i][3] = fmaf(p, vv.w, o[i][3]);
            }
        }
    }
    __syncthreads();

    // ---- write ctx in [B, S, D] layout ----
    const int b = bh >> 4, h = bh & 15;
#pragma unroll
    for (int i = 0; i < 4; ++i) {
        const int row = (ty<<2) + i;
        const float inv = 1.f / l_s[row];
        float4 r;
        r.x = o[i][0]*inv; r.y = o[i][1]*inv; r.z = o[i][2]*inv; r.w = o[i][3]*inv;
        *(float4*)&ctx[((size_t)(b*SEQLEN) + qt*64 + row) * DMODEL + h*DKDIM + (tx<<2)] = r;
    }
}

extern "C" void kernel_launch(void* const* d_in, const int* in_sizes, int n_in,
                              void* d_out, int out_size, void* d_ws, size_t ws_size,
                              hipStream_t stream)
{
    const float* x  = (const float*)d_in[0];
    const float* Wq = (const float*)d_in[1];
    const float* bq = (const float*)d_in[2];
    const float* Wk = (const float*)d_in[3];
    const float* bk = (const float*)d_in[4];
    const float* Wv = (const float*)d_in[5];
    const float* bv = (const float*)d_in[6];
    const float* Wo = (const float*)d_in[7];
    const float* bo = (const float*)d_in[8];
    float* out = (float*)d_out;

    const size_t elems = (size_t)NBATCH * SEQLEN * DMODEL;   // 8,388,608
    float* q   = (float*)d_ws;
    float* kk  = q   + elems;
    float* vv  = kk  + elems;
    float* ctx = vv  + elems;

    dim3 blk(256);
    qkv_gemm_kernel<<<dim3(DMODEL/128, (NBATCH*SEQLEN)/128, 3), blk, 0, stream>>>(
        x, Wq, bq, Wk, bk, Wv, bv, q, kk, vv);
    attn_kernel<<<dim3(SEQLEN/64, NBATCH*NHEADS), blk, 0, stream>>>(q, kk, vv, ctx);
    out_gemm_kernel<<<dim3(DMODEL/128, (NBATCH*SEQLEN)/128, 1), blk, 0, stream>>>(
        ctx, Wo, bo, out);
}

// Round 2
// 291.719 us; speedup vs baseline: 6.5368x; 6.5368x over previous
//
#include <hip/hip_runtime.h>
#include <math.h>

#define DMODEL 1024
#define NHEADS 16
#define DKDIM  64
#define SEQLEN 2048
#define NBATCH 4
#define MTOT   (NBATCH * SEQLEN)   // 8192

typedef __attribute__((ext_vector_type(8))) short short8;
typedef __attribute__((ext_vector_type(4))) float f32x4;

__device__ __forceinline__ unsigned short f2bf(float x) {
    unsigned u = __builtin_bit_cast(unsigned, x);
    unsigned r = (u + 0x7fffu + ((u >> 16) & 1u)) >> 16;
    return (unsigned short)r;
}

__device__ __forceinline__ void gload16(const void* g, void* l) {
    __builtin_amdgcn_global_load_lds(
        (const __attribute__((address_space(1))) void*)g,
        (__attribute__((address_space(3))) void*)l, 16, 0, 0);
}

// ============ convert x (f32 -> bf16 flat) ============
__global__ __launch_bounds__(256)
void convert_x_kernel(const float* __restrict__ x, unsigned short* __restrict__ xb)
{
    const size_t i = ((size_t)blockIdx.x * 256 + threadIdx.x) * 8;
    const float4 a = *(const float4*)&x[i];
    const float4 b = *(const float4*)&x[i + 4];
    union { unsigned short u[8]; uint4 q; } p;
    p.u[0] = f2bf(a.x); p.u[1] = f2bf(a.y); p.u[2] = f2bf(a.z); p.u[3] = f2bf(a.w);
    p.u[4] = f2bf(b.x); p.u[5] = f2bf(b.y); p.u[6] = f2bf(b.z); p.u[7] = f2bf(b.w);
    *(uint4*)&xb[i] = p.q;
}

// ============ convert + transpose W: W[k][n] f32 -> Wt[n][k] bf16 ============
__global__ __launch_bounds__(256)
void convert_w_kernel(const float* __restrict__ W0, const float* __restrict__ W1,
                      const float* __restrict__ W2, const float* __restrict__ W3,
                      unsigned short* __restrict__ wt)
{
    const int z = blockIdx.z;
    const float* W = (z == 0) ? W0 : (z == 1) ? W1 : (z == 2) ? W2 : W3;
    unsigned short* dst = wt + (size_t)z * DMODEL * DMODEL;
    const int n0 = blockIdx.x * 64, k0 = blockIdx.y * 64;
    __shared__ float T[64][65];
    const int t = threadIdx.x;
    const int r0 = t >> 4, c0 = (t & 15) << 2;
#pragma unroll
    for (int u = 0; u < 4; ++u) {
        const float4 wv = *(const float4*)&W[(size_t)(k0 + r0 + u * 16) * DMODEL + n0 + c0];
        T[c0 + 0][r0 + u * 16] = wv.x;
        T[c0 + 1][r0 + u * 16] = wv.y;
        T[c0 + 2][r0 + u * 16] = wv.z;
        T[c0 + 3][r0 + u * 16] = wv.w;
    }
    __syncthreads();
    const int rn = t >> 2, ck = (t & 3) << 4;
    union { unsigned short u16[16]; uint4 q[2]; } pk;
#pragma unroll
    for (int e = 0; e < 16; ++e) pk.u16[e] = f2bf(T[rn][ck + e]);
    *(uint4*)&dst[(size_t)(n0 + rn) * DMODEL + k0 + ck]     = pk.q[0];
    *(uint4*)&dst[(size_t)(n0 + rn) * DMODEL + k0 + ck + 8] = pk.q[1];
}

// ============ bf16 MFMA GEMM: C[M,1024] = A[M,1024] @ Wt[n][k]^T + bias ============
// OMODE 0: bf16 flat [m][n];  OMODE 1: bf16 V-transposed [B,H,Dk,S];  OMODE 2: f32 flat.
template<int OMODE>
__device__ __forceinline__
void gemm_core(const unsigned short* __restrict__ A, const unsigned short* __restrict__ Bt,
               const float* __restrict__ bias, void* __restrict__ outv)
{
    __shared__ __align__(16) char As[128 * 128];   // [128 rows][64 k] bf16, swizzled
    __shared__ __align__(16) char Bs[128 * 128];

    const int t  = threadIdx.x;
    const int l  = t & 63, w = t >> 6;
    const int g  = (l >> 4), lr = l & 15;
    const int wr = w >> 1, wc = w & 1;
    const int swz = (lr & 7) << 4;
    const int m0 = blockIdx.y << 7, n0 = blockIdx.x << 7;

    f32x4 acc[4][4];
#pragma unroll
    for (int i = 0; i < 4; ++i)
#pragma unroll
        for (int j = 0; j < 4; ++j) acc[i][j] = (f32x4){0.f, 0.f, 0.f, 0.f};

    for (int k0 = 0; k0 < DMODEL; k0 += 64) {
        __syncthreads();
#pragma unroll
        for (int qd = 0; qd < 4; ++qd) {
            const int o   = (t + qd * 256) << 4;
            const int row = o >> 7;
            const int c   = (o & 127) ^ ((row & 7) << 4);
            gload16((const char*)A  + (((size_t)(m0 + row) * DMODEL + k0) << 1) + c, As + o);
            gload16((const char*)Bt + (((size_t)(n0 + row) * DMODEL + k0) << 1) + c, Bs + o);
        }
        __syncthreads();

        short8 af[4][2], bf[4][2];
#pragma unroll
        for (int i = 0; i < 4; ++i)
#pragma unroll
            for (int kk = 0; kk < 2; ++kk) {
                const int off = (kk * 64 + g * 16) ^ swz;
                af[i][kk] = *(const short8*)(As + (wr * 64 + i * 16 + lr) * 128 + off);
                bf[i][kk] = *(const short8*)(Bs + (wc * 64 + i * 16 + lr) * 128 + off);
            }
#pragma unroll
        for (int kk = 0; kk < 2; ++kk)
#pragma unroll
            for (int i = 0; i < 4; ++i)
#pragma unroll
                for (int j = 0; j < 4; ++j)
                    acc[i][j] = __builtin_amdgcn_mfma_f32_16x16x32_bf16(
                        af[i][kk], bf[j][kk], acc[i][j], 0, 0, 0);
    }

    float bj[4];
#pragma unroll
    for (int j = 0; j < 4; ++j) bj[j] = bias[n0 + wc * 64 + j * 16 + lr];

#pragma unroll
    for (int i = 0; i < 4; ++i)
#pragma unroll
        for (int j = 0; j < 4; ++j) {
            const int mb = m0 + wr * 64 + i * 16 + g * 4;
            const int n  = n0 + wc * 64 + j * 16 + lr;
            float v[4];
#pragma unroll
            for (int r = 0; r < 4; ++r) v[r] = acc[i][j][r] + bj[j];
            if (OMODE == 0) {
                unsigned short* outp = (unsigned short*)outv;
#pragma unroll
                for (int r = 0; r < 4; ++r)
                    outp[(size_t)(mb + r) * DMODEL + n] = f2bf(v[r]);
            } else if (OMODE == 1) {
                unsigned short* outp = (unsigned short*)outv;
                const int b = mb >> 11, s = mb & (SEQLEN - 1);
                const size_t idx = (((size_t)(b * NHEADS + (n >> 6)) * DKDIM + (n & 63)) << 11) + s;
                uint2 pk;
                pk.x = (unsigned)f2bf(v[0]) | ((unsigned)f2bf(v[1]) << 16);
                pk.y = (unsigned)f2bf(v[2]) | ((unsigned)f2bf(v[3]) << 16);
                *(uint2*)&outp[idx] = pk;
            } else {
                float* outp = (float*)outv;
#pragma unroll
                for (int r = 0; r < 4; ++r)
                    outp[(size_t)(mb + r) * DMODEL + n] = v[r];
            }
        }
}

__global__ __launch_bounds__(256)
void qk_gemm_kernel(const unsigned short* __restrict__ xb, const unsigned short* __restrict__ wt,
                    const float* __restrict__ bq, const float* __restrict__ bk,
                    unsigned short* __restrict__ Qb, unsigned short* __restrict__ Kb)
{
    if (blockIdx.z == 0) gemm_core<0>(xb, wt,                  bq, Qb);
    else                 gemm_core<0>(xb, wt + DMODEL * DMODEL, bk, Kb);
}

__global__ __launch_bounds__(256)
void v_gemm_kernel(const unsigned short* __restrict__ xb, const unsigned short* __restrict__ wt,
                   const float* __restrict__ bv, unsigned short* __restrict__ Vt)
{
    gemm_core<1>(xb, wt + 2 * DMODEL * DMODEL, bv, Vt);
}

__global__ __launch_bounds__(256)
void out_gemm_kernel(const unsigned short* __restrict__ ctx, const unsigned short* __restrict__ wt,
                     const float* __restrict__ bo, float* __restrict__ out)
{
    gemm_core<2>(ctx, wt + 3 * DMODEL * DMODEL, bo, out);
}

// ============ bf16 MFMA flash attention ============
// Block: 256 thr = 4 waves; 128 q-rows/block (32/wave); KV tiles of 64.
// S^T = mfma(K, Q)  -> softmax per q-col (per-lane scalars)
// ctx^T = mfma(Vt, P^T), P^T staged per-wave in LDS.
__global__ __launch_bounds__(256)
void attn_kernel(const unsigned short* __restrict__ Qb, const unsigned short* __restrict__ Kb,
                 const unsigned short* __restrict__ Vt, unsigned short* __restrict__ ctx)
{
    __shared__ __align__(16) char Ks[64 * 128];    // [64 kv][64 dk] bf16, swizzled
    __shared__ __align__(16) char Vs[64 * 128];    // [64 d][64 kv]  bf16, swizzled
    __shared__ __align__(16) char Ps[4 * 32 * 128]; // per-wave [32 q][64 kv] bf16, swizzled

    const int t  = threadIdx.x;
    const int l  = t & 63, w = t >> 6;
    const int g  = (l >> 4), lr = l & 15;
    const int swz = (lr & 7) << 4;
    const int qt = blockIdx.x;          // 0..15
    const int bh = blockIdx.y;          // 0..63
    const int b  = bh >> 4, h = bh & 15;
    const int coln = h * DKDIM;

    const size_t qrow0 = (size_t)b * SEQLEN + qt * 128;
    const size_t krow0 = (size_t)b * SEQLEN;
    char* Pw = Ps + w * 4096;

    // Q fragments in registers (B-operand layout): row q, 8 consecutive dk
    short8 qf[2][2];
#pragma unroll
    for (int j = 0; j < 2; ++j)
#pragma unroll
        for (int kk = 0; kk < 2; ++kk)
            qf[j][kk] = *(const short8*)(Qb + (qrow0 + w * 32 + j * 16 + lr) * DMODEL
                                         + coln + kk * 32 + g * 8);

    float m_j[2] = {-1e30f, -1e30f};
    float l_j[2] = {0.f, 0.f};
    f32x4 acc[4][2];
#pragma unroll
    for (int i = 0; i < 4; ++i)
#pragma unroll
        for (int j = 0; j < 2; ++j) acc[i][j] = (f32x4){0.f, 0.f, 0.f, 0.f};

    const float CEXP = 0.125f * 1.44269504088896341f;   // scale * log2(e)

    for (int kt = 0; kt < SEQLEN / 64; ++kt) {
        const int kv0 = kt * 64;
        __syncthreads();
#pragma unroll
        for (int qd = 0; qd < 2; ++qd) {
            const int o   = (t + qd * 256) << 4;
            const int row = o >> 7;
            const int c   = (o & 127) ^ ((row & 7) << 4);
            gload16((const char*)Kb + (((krow0 + kv0 + row) * DMODEL + coln) << 1) + c, Ks + o);
            gload16((const char*)Vt + ((((size_t)(b * NHEADS + h) * DKDIM + row) * SEQLEN + kv0) << 1) + c,
                    Vs + o);
        }
        __syncthreads();

        // ---- S^T[kv][q] = K · Q^T ----
        f32x4 sc[4][2];
#pragma unroll
        for (int i = 0; i < 4; ++i) {
            sc[i][0] = (f32x4){0.f, 0.f, 0.f, 0.f};
            sc[i][1] = (f32x4){0.f, 0.f, 0.f, 0.f};
            short8 kf[2];
#pragma unroll
            for (int kk = 0; kk < 2; ++kk)
                kf[kk] = *(const short8*)(Ks + (i * 16 + lr) * 128 + ((kk * 64 + g * 16) ^ swz));
#pragma unroll
            for (int kk = 0; kk < 2; ++kk)
#pragma unroll
                for (int j = 0; j < 2; ++j)
                    sc[i][j] = __builtin_amdgcn_mfma_f32_16x16x32_bf16(
                        kf[kk], qf[j][kk], sc[i][j], 0, 0, 0);
        }

        // ---- online softmax per q-column ----
        float alpha[2];
#pragma unroll
        for (int j = 0; j < 2; ++j) {
            float mx = sc[0][j][0];
#pragma unroll
            for (int i = 0; i < 4; ++i)
#pragma unroll
                for (int r = 0; r < 4; ++r) mx = fmaxf(mx, sc[i][j][r]);
            mx = fmaxf(mx, __shfl_xor(mx, 16));
            mx = fmaxf(mx, __shfl_xor(mx, 32));
            const float mnew = fmaxf(m_j[j], mx);
            alpha[j] = exp2f((m_j[j] - mnew) * CEXP);
            m_j[j] = mnew;
            float ps = 0.f;
            const int q = j * 16 + lr;
#pragma unroll
            for (int i = 0; i < 4; ++i) {
                float p0 = exp2f((sc[i][j][0] - mnew) * CEXP);
                float p1 = exp2f((sc[i][j][1] - mnew) * CEXP);
                float p2 = exp2f((sc[i][j][2] - mnew) * CEXP);
                float p3 = exp2f((sc[i][j][3] - mnew) * CEXP);
                ps += (p0 + p1) + (p2 + p3);
                uint2 pk;
                pk.x = (unsigned)f2bf(p0) | ((unsigned)f2bf(p1) << 16);
                pk.y = (unsigned)f2bf(p2) | ((unsigned)f2bf(p3) << 16);
                *(uint2*)(Pw + q * 128 + ((i * 32 + g * 8) ^ swz)) = pk;
            }
            ps += __shfl_xor(ps, 16);
            ps += __shfl_xor(ps, 32);
            l_j[j] = l_j[j] * alpha[j] + ps;
        }

        // ---- rescale + PV: ctx^T += Vt · P^T ----
#pragma unroll
        for (int i = 0; i < 4; ++i)
#pragma unroll
            for (int j = 0; j < 2; ++j) {
#pragma unroll
                for (int r = 0; r < 4; ++r) acc[i][j][r] *= alpha[j];
            }

        short8 pf[2][2];
#pragma unroll
        for (int j = 0; j < 2; ++j)
#pragma unroll
            for (int kk = 0; kk < 2; ++kk)
                pf[j][kk] = *(const short8*)(Pw + (j * 16 + lr) * 128 + ((kk * 64 + g * 16) ^ swz));

#pragma unroll
        for (int i = 0; i < 4; ++i) {
            short8 vf[2];
#pragma unroll
            for (int kk = 0; kk < 2; ++kk)
                vf[kk] = *(const short8*)(Vs + (i * 16 + lr) * 128 + ((kk * 64 + g * 16) ^ swz));
#pragma unroll
            for (int kk = 0; kk < 2; ++kk)
#pragma unroll
                for (int j = 0; j < 2; ++j)
                    acc[i][j] = __builtin_amdgcn_mfma_f32_16x16x32_bf16(
                        vf[kk], pf[j][kk], acc[i][j], 0, 0, 0);
        }
    }

    // ---- epilogue: ctx[token][h*64+d] bf16 ----
#pragma unroll
    for (int j = 0; j < 2; ++j) {
        const float inv = 1.f / l_j[j];
        const size_t row = qrow0 + w * 32 + j * 16 + lr;
#pragma unroll
        for (int i = 0; i < 4; ++i) {
            const int col = coln + i * 16 + g * 4;
            uint2 pk;
            pk.x = (unsigned)f2bf(acc[i][j][0] * inv) | ((unsigned)f2bf(acc[i][j][1] * inv) << 16);
            pk.y = (unsigned)f2bf(acc[i][j][2] * inv) | ((unsigned)f2bf(acc[i][j][3] * inv) << 16);
            *(uint2*)&ctx[row * DMODEL + col] = pk;
        }
    }
}

extern "C" void kernel_launch(void* const* d_in, const int* in_sizes, int n_in,
                              void* d_out, int out_size, void* d_ws, size_t ws_size,
                              hipStream_t stream)
{
    const float* x  = (const float*)d_in[0];
    const float* Wq = (const float*)d_in[1];
    const float* bq = (const float*)d_in[2];
    const float* Wk = (const float*)d_in[3];
    const float* bk = (const float*)d_in[4];
    const float* Wv = (const float*)d_in[5];
    const float* bv = (const float*)d_in[6];
    const float* Wo = (const float*)d_in[7];
    const float* bo = (const float*)d_in[8];
    float* out = (float*)d_out;

    const size_t NE = (size_t)MTOT * DMODEL;           // 8,388,608
    unsigned short* xb  = (unsigned short*)d_ws;
    unsigned short* wt  = xb  + NE;                     // 4 transposed weights
    unsigned short* Qb  = wt  + (size_t)4 * DMODEL * DMODEL;
    unsigned short* Kb  = Qb  + NE;
    unsigned short* Vt  = Kb  + NE;
    unsigned short* ctx = Vt  + NE;

    convert_x_kernel<<<dim3(NE / (256 * 8)), 256, 0, stream>>>(x, xb);
    convert_w_kernel<<<dim3(16, 16, 4), 256, 0, stream>>>(Wq, Wk, Wv, Wo, wt);
    qk_gemm_kernel<<<dim3(8, 64, 2), 256, 0, stream>>>(xb, wt, bq, bk, Qb, Kb);
    v_gemm_kernel<<<dim3(8, 64), 256, 0, stream>>>(xb, wt, bv, Vt);
    attn_kernel<<<dim3(16, 64), 256, 0, stream>>>(Qb, Kb, Vt, ctx);
    out_gemm_kernel<<<dim3(8, 64), 256, 0, stream>>>(ctx, wt, bo, out);
}

// Round 3
// 223.811 us; speedup vs baseline: 8.5201x; 1.3034x over previous
//
#include <hip/hip_runtime.h>
#include <math.h>

#define DMODEL 1024
#define NHEADS 16
#define DKDIM  64
#define SEQLEN 2048
#define NBATCH 4
#define MTOT   (NBATCH * SEQLEN)   // 8192

typedef __attribute__((ext_vector_type(8)))  short short8;
typedef __attribute__((ext_vector_type(4)))  float f32x4;
typedef __attribute__((ext_vector_type(16))) float f32x16;

__device__ __forceinline__ unsigned short f2bf(float x) {
    unsigned u = __builtin_bit_cast(unsigned, x);
    unsigned r = (u + 0x7fffu + ((u >> 16) & 1u)) >> 16;
    return (unsigned short)r;
}

__device__ __forceinline__ void gload16(const void* g, void* l) {
    __builtin_amdgcn_global_load_lds(
        (const __attribute__((address_space(1))) void*)g,
        (__attribute__((address_space(3))) void*)l, 16, 0, 0);
}

// ============ convert x (f32 -> bf16 flat) ============
__global__ __launch_bounds__(256)
void convert_x_kernel(const float* __restrict__ x, unsigned short* __restrict__ xb)
{
    const size_t i = ((size_t)blockIdx.x * 256 + threadIdx.x) * 8;
    const float4 a = *(const float4*)&x[i];
    const float4 b = *(const float4*)&x[i + 4];
    union { unsigned short u[8]; uint4 q; } p;
    p.u[0] = f2bf(a.x); p.u[1] = f2bf(a.y); p.u[2] = f2bf(a.z); p.u[3] = f2bf(a.w);
    p.u[4] = f2bf(b.x); p.u[5] = f2bf(b.y); p.u[6] = f2bf(b.z); p.u[7] = f2bf(b.w);
    *(uint4*)&xb[i] = p.q;
}

// ============ convert + transpose W: W[k][n] f32 -> Wt[n][k] bf16 ============
__global__ __launch_bounds__(256)
void convert_w_kernel(const float* __restrict__ W0, const float* __restrict__ W1,
                      const float* __restrict__ W2, const float* __restrict__ W3,
                      unsigned short* __restrict__ wt)
{
    const int z = blockIdx.z;
    const float* W = (z == 0) ? W0 : (z == 1) ? W1 : (z == 2) ? W2 : W3;
    unsigned short* dst = wt + (size_t)z * DMODEL * DMODEL;
    const int n0 = blockIdx.x * 64, k0 = blockIdx.y * 64;
    __shared__ float T[64][65];
    const int t = threadIdx.x;
    const int r0 = t >> 4, c0 = (t & 15) << 2;
#pragma unroll
    for (int u = 0; u < 4; ++u) {
        const float4 wv = *(const float4*)&W[(size_t)(k0 + r0 + u * 16) * DMODEL + n0 + c0];
        T[c0 + 0][r0 + u * 16] = wv.x;
        T[c0 + 1][r0 + u * 16] = wv.y;
        T[c0 + 2][r0 + u * 16] = wv.z;
        T[c0 + 3][r0 + u * 16] = wv.w;
    }
    __syncthreads();
    const int rn = t >> 2, ck = (t & 3) << 4;
    union { unsigned short u16[16]; uint4 q[2]; } pk;
#pragma unroll
    for (int e = 0; e < 16; ++e) pk.u16[e] = f2bf(T[rn][ck + e]);
    *(uint4*)&dst[(size_t)(n0 + rn) * DMODEL + k0 + ck]     = pk.q[0];
    *(uint4*)&dst[(size_t)(n0 + rn) * DMODEL + k0 + ck + 8] = pk.q[1];
}

// ============ bf16 MFMA GEMM ============
// OMODE 0: bf16 flat [m][n];  OMODE 1: bf16 V-transposed [B,H,Dk,S];  OMODE 2: f32 flat.
template<int OMODE>
__device__ __forceinline__
void gemm_core(const unsigned short* __restrict__ A, const unsigned short* __restrict__ Bt,
               const float* __restrict__ bias, void* __restrict__ outv, const float scl)
{
    __shared__ __align__(16) char As[128 * 128];
    __shared__ __align__(16) char Bs[128 * 128];

    const int t  = threadIdx.x;
    const int l  = t & 63, w = t >> 6;
    const int g  = (l >> 4), lr = l & 15;
    const int wr = w >> 1, wc = w & 1;
    const int swz = (lr & 7) << 4;
    const int m0 = blockIdx.y << 7, n0 = blockIdx.x << 7;

    f32x4 acc[4][4];
#pragma unroll
    for (int i = 0; i < 4; ++i)
#pragma unroll
        for (int j = 0; j < 4; ++j) acc[i][j] = (f32x4){0.f, 0.f, 0.f, 0.f};

    for (int k0 = 0; k0 < DMODEL; k0 += 64) {
        __syncthreads();
#pragma unroll
        for (int qd = 0; qd < 4; ++qd) {
            const int o   = (t + qd * 256) << 4;
            const int row = o >> 7;
            const int c   = (o & 127) ^ ((row & 7) << 4);
            gload16((const char*)A  + (((size_t)(m0 + row) * DMODEL + k0) << 1) + c, As + o);
            gload16((const char*)Bt + (((size_t)(n0 + row) * DMODEL + k0) << 1) + c, Bs + o);
        }
        __syncthreads();

        short8 af[4][2], bf[4][2];
#pragma unroll
        for (int i = 0; i < 4; ++i)
#pragma unroll
            for (int kk = 0; kk < 2; ++kk) {
                const int off = (kk * 64 + g * 16) ^ swz;
                af[i][kk] = *(const short8*)(As + (wr * 64 + i * 16 + lr) * 128 + off);
                bf[i][kk] = *(const short8*)(Bs + (wc * 64 + i * 16 + lr) * 128 + off);
            }
        __builtin_amdgcn_s_setprio(1);
#pragma unroll
        for (int kk = 0; kk < 2; ++kk)
#pragma unroll
            for (int i = 0; i < 4; ++i)
#pragma unroll
                for (int j = 0; j < 4; ++j)
                    acc[i][j] = __builtin_amdgcn_mfma_f32_16x16x32_bf16(
                        af[i][kk], bf[j][kk], acc[i][j], 0, 0, 0);
        __builtin_amdgcn_s_setprio(0);
    }

    float bj[4];
#pragma unroll
    for (int j = 0; j < 4; ++j) bj[j] = bias[n0 + wc * 64 + j * 16 + lr];

#pragma unroll
    for (int i = 0; i < 4; ++i)
#pragma unroll
        for (int j = 0; j < 4; ++j) {
            const int mb = m0 + wr * 64 + i * 16 + g * 4;
            const int n  = n0 + wc * 64 + j * 16 + lr;
            float v[4];
#pragma unroll
            for (int r = 0; r < 4; ++r) v[r] = (acc[i][j][r] + bj[j]) * scl;
            if (OMODE == 0) {
                unsigned short* outp = (unsigned short*)outv;
#pragma unroll
                for (int r = 0; r < 4; ++r)
                    outp[(size_t)(mb + r) * DMODEL + n] = f2bf(v[r]);
            } else if (OMODE == 1) {
                unsigned short* outp = (unsigned short*)outv;
                const int b = mb >> 11, s = mb & (SEQLEN - 1);
                const size_t idx = (((size_t)(b * NHEADS + (n >> 6)) * DKDIM + (n & 63)) << 11) + s;
                uint2 pk;
                pk.x = (unsigned)f2bf(v[0]) | ((unsigned)f2bf(v[1]) << 16);
                pk.y = (unsigned)f2bf(v[2]) | ((unsigned)f2bf(v[3]) << 16);
                *(uint2*)&outp[idx] = pk;
            } else {
                float* outp = (float*)outv;
#pragma unroll
                for (int r = 0; r < 4; ++r)
                    outp[(size_t)(mb + r) * DMODEL + n] = v[r];
            }
        }
}

#define QSCALE 0.1803368801111137f   // 0.125 * log2(e): scores come out in log2 units

__global__ __launch_bounds__(256)
void qkv_gemm_kernel(const unsigned short* __restrict__ xb, const unsigned short* __restrict__ wt,
                     const float* __restrict__ bq, const float* __restrict__ bk,
                     const float* __restrict__ bv,
                     unsigned short* __restrict__ Qb, unsigned short* __restrict__ Kb,
                     unsigned short* __restrict__ Vt)
{
    if (blockIdx.z == 0)      gemm_core<0>(xb, wt,                      bq, Qb, QSCALE);
    else if (blockIdx.z == 1) gemm_core<0>(xb, wt + DMODEL * DMODEL,     bk, Kb, 1.0f);
    else                      gemm_core<1>(xb, wt + 2 * DMODEL * DMODEL, bv, Vt, 1.0f);
}

__global__ __launch_bounds__(256)
void out_gemm_kernel(const unsigned short* __restrict__ ctx, const unsigned short* __restrict__ wt,
                     const float* __restrict__ bo, float* __restrict__ out)
{
    gemm_core<2>(ctx, wt + 3 * DMODEL * DMODEL, bo, out, 1.0f);
}

// ============ bf16 MFMA flash attention, 32x32x16, in-register P ============
// 512 thr = 8 waves, 32 q-rows/wave (256 q/block). KV tiles of 64, double-buffered.
// S^T = mfma(K, Q): lane owns one q-column -> softmax is in-lane + shfl_xor(32).
// PV B-fragments built in-register via v_cvt_pk_bf16_f32 + v_permlane32_swap_b32.
__global__ __launch_bounds__(512)
void attn_kernel(const unsigned short* __restrict__ Qb, const unsigned short* __restrict__ Kb,
                 const unsigned short* __restrict__ Vt, unsigned short* __restrict__ ctx)
{
    __shared__ __align__(16) char smem[32768];   // K bufs [0,16K), V bufs [16K,32K)

    const int t   = threadIdx.x;
    const int l   = t & 63, w = t >> 6;
    const int q32 = l & 31, hi = l >> 5;
    const int swz = (q32 & 7) << 4;
    const int qt  = blockIdx.x;          // 0..7
    const int bh  = blockIdx.y;          // 0..63
    const int b   = bh >> 4, h = bh & 15;
    const int coln = h * DKDIM;

    const size_t qrow  = (size_t)b * SEQLEN + qt * 256 + w * 32 + q32;
    const size_t krow0 = (size_t)b * SEQLEN;
    const size_t vbase = (size_t)(b * NHEADS + h) * DKDIM * SEQLEN;

    // Q fragments in registers (already scaled by 0.125*log2e in projection)
    short8 qf[4];
#pragma unroll
    for (int kk = 0; kk < 4; ++kk)
        qf[kk] = *(const short8*)(Qb + qrow * DMODEL + coln + kk * 16 + hi * 8);

    f32x16 po[2];
#pragma unroll
    for (int r = 0; r < 16; ++r) { po[0][r] = 0.f; po[1][r] = 0.f; }
    float m = -1e30f, lsum = 0.f;

    const int so  = t << 4;              // staging offset, 0..8191
    const int srow = so >> 7;
    const int sc_ = (so & 127) ^ ((srow & 7) << 4);

#define STAGE(buf, kt)                                                                  \
    do {                                                                                \
        gload16((const char*)Kb + (((krow0 + (kt) * 64 + srow) * DMODEL + coln) << 1) + sc_, \
                smem + (buf) * 8192 + so);                                              \
        gload16((const char*)Vt + ((vbase + (size_t)srow * SEQLEN + (kt) * 64) << 1) + sc_,  \
                smem + 16384 + (buf) * 8192 + so);                                      \
    } while (0)

    STAGE(0, 0);
    __syncthreads();

    for (int kt = 0; kt < SEQLEN / 64; ++kt) {
        const int buf = kt & 1;
        const char* Kbuf = smem + buf * 8192;
        const char* Vbuf = smem + 16384 + buf * 8192;
        if (kt + 1 < SEQLEN / 64) STAGE(buf ^ 1, kt + 1);

        // ---- S^T[kv][q] ----
        f32x16 sc[2];
#pragma unroll
        for (int r = 0; r < 16; ++r) { sc[0][r] = 0.f; sc[1][r] = 0.f; }
#pragma unroll
        for (int i = 0; i < 2; ++i) {
            short8 kf[4];
#pragma unroll
            for (int kk = 0; kk < 4; ++kk)
                kf[kk] = *(const short8*)(Kbuf + (i * 32 + q32) * 128 + ((kk * 32 + hi * 16) ^ swz));
            __builtin_amdgcn_s_setprio(1);
#pragma unroll
            for (int kk = 0; kk < 4; ++kk)
                sc[i] = __builtin_amdgcn_mfma_f32_32x32x16_bf16(kf[kk], qf[kk], sc[i], 0, 0, 0);
            __builtin_amdgcn_s_setprio(0);
        }

        // ---- online softmax (scores already in log2 units) ----
        float mx = sc[0][0];
#pragma unroll
        for (int r = 1; r < 16; ++r) mx = fmaxf(mx, sc[0][r]);
#pragma unroll
        for (int r = 0; r < 16; ++r) mx = fmaxf(mx, sc[1][r]);
        mx = fmaxf(mx, __shfl_xor(mx, 32));

        float alpha = 1.0f;
        if (!__all(mx <= m + 11.0f)) {            // defer-max (T13)
            const float mn = fmaxf(m, mx);
            alpha = exp2f(m - mn);
            m = mn;
#pragma unroll
            for (int r = 0; r < 16; ++r) { po[0][r] *= alpha; po[1][r] *= alpha; }
        }
        float ps = 0.f;
#pragma unroll
        for (int i = 0; i < 2; ++i)
#pragma unroll
            for (int r = 0; r < 16; ++r) {
                const float p = exp2f(sc[i][r] - m);
                sc[i][r] = p;
                ps += p;
            }
        ps += __shfl_xor(ps, 32);
        lsum = lsum * alpha + ps;

        // ---- build PV B-fragments in-register (T12) ----
        short8 pf[4];
#pragma unroll
        for (int ks = 0; ks < 4; ++ks) {
            const f32x16& st = sc[ks >> 1];
            const int bse = (ks & 1) * 8;
            unsigned wA0, wA1, wB0, wB1;
            asm("v_cvt_pk_bf16_f32 %0, %1, %2" : "=v"(wA0) : "v"(st[bse + 0]), "v"(st[bse + 1]));
            asm("v_cvt_pk_bf16_f32 %0, %1, %2" : "=v"(wA1) : "v"(st[bse + 2]), "v"(st[bse + 3]));
            asm("v_cvt_pk_bf16_f32 %0, %1, %2" : "=v"(wB0) : "v"(st[bse + 4]), "v"(st[bse + 5]));
            asm("v_cvt_pk_bf16_f32 %0, %1, %2" : "=v"(wB1) : "v"(st[bse + 6]), "v"(st[bse + 7]));
            asm volatile("v_permlane32_swap_b32 %0, %1" : "+v"(wA0), "+v"(wB0));
            asm volatile("v_permlane32_swap_b32 %0, %1" : "+v"(wA1), "+v"(wB1));
            union { unsigned u[4]; short8 s; } pk;
            pk.u[0] = wA0; pk.u[1] = wA1; pk.u[2] = wB0; pk.u[3] = wB1;
            pf[ks] = pk.s;
        }

        // ---- PV: ctx^T += Vt . P^T ----
#pragma unroll
        for (int i = 0; i < 2; ++i) {
            short8 vf[4];
#pragma unroll
            for (int ks = 0; ks < 4; ++ks)
                vf[ks] = *(const short8*)(Vbuf + (i * 32 + q32) * 128 + ((ks * 32 + hi * 16) ^ swz));
            __builtin_amdgcn_s_setprio(1);
#pragma unroll
            for (int ks = 0; ks < 4; ++ks)
                po[i] = __builtin_amdgcn_mfma_f32_32x32x16_bf16(vf[ks], pf[ks], po[i], 0, 0, 0);
            __builtin_amdgcn_s_setprio(0);
        }

        __syncthreads();
    }

    // ---- epilogue: transpose through LDS, coalesced bf16 ctx write ----
    const float inv = 1.0f / lsum;
    char* T = smem + w * 4096;            // per-wave [32 q][64 d] bf16, swizzled
#pragma unroll
    for (int i = 0; i < 2; ++i)
#pragma unroll
        for (int g4 = 0; g4 < 4; ++g4) {
            const int d0 = i * 32 + g4 * 8 + hi * 4;
            uint2 pk;
            pk.x = (unsigned)f2bf(po[i][g4 * 4 + 0] * inv) | ((unsigned)f2bf(po[i][g4 * 4 + 1] * inv) << 16);
            pk.y = (unsigned)f2bf(po[i][g4 * 4 + 2] * inv) | ((unsigned)f2bf(po[i][g4 * 4 + 3] * inv) << 16);
            *(uint2*)(T + ((q32 * 128 + d0 * 2) ^ swz)) = pk;
        }
    __syncthreads();
#pragma unroll
    for (int pass = 0; pass < 4; ++pass) {
        const int o   = (l + pass * 64) << 4;    // 0..4095
        const int row = o >> 7;
        const int c   = o & 127;
        const uint4 val = *(const uint4*)(T + (o ^ ((row & 7) << 4)));
        const size_t token = (size_t)b * SEQLEN + qt * 256 + w * 32 + row;
        *(uint4*)&ctx[token * DMODEL + coln + (c >> 1)] = val;
    }
#undef STAGE
}

extern "C" void kernel_launch(void* const* d_in, const int* in_sizes, int n_in,
                              void* d_out, int out_size, void* d_ws, size_t ws_size,
                              hipStream_t stream)
{
    const float* x  = (const float*)d_in[0];
    const float* Wq = (const float*)d_in[1];
    const float* bq = (const float*)d_in[2];
    const float* Wk = (const float*)d_in[3];
    const float* bk = (const float*)d_in[4];
    const float* Wv = (const float*)d_in[5];
    const float* bv = (const float*)d_in[6];
    const float* Wo = (const float*)d_in[7];
    const float* bo = (const float*)d_in[8];
    float* out = (float*)d_out;

    const size_t NE = (size_t)MTOT * DMODEL;
    unsigned short* xb  = (unsigned short*)d_ws;
    unsigned short* wt  = xb  + NE;
    unsigned short* Qb  = wt  + (size_t)4 * DMODEL * DMODEL;
    unsigned short* Kb  = Qb  + NE;
    unsigned short* Vt  = Kb  + NE;
    unsigned short* ctx = Vt  + NE;

    convert_x_kernel<<<dim3(NE / (256 * 8)), 256, 0, stream>>>(x, xb);
    convert_w_kernel<<<dim3(16, 16, 4), 256, 0, stream>>>(Wq, Wk, Wv, Wo, wt);
    qkv_gemm_kernel<<<dim3(8, 64, 3), 256, 0, stream>>>(xb, wt, bq, bk, bv, Qb, Kb, Vt);
    attn_kernel<<<dim3(SEQLEN / 256, NBATCH * NHEADS), dim3(512), 0, stream>>>(Qb, Kb, Vt, ctx);
    out_gemm_kernel<<<dim3(8, 64), 256, 0, stream>>>(ctx, wt, bo, out);
}